// Round 1
// baseline (182.167 us; speedup 1.0000x reference)
//
#include <hip/hip_runtime.h>

// NormEMAVectorQuantizer on MI355X (gfx950)
// N=8192 tokens, C=32, K=8192 codes, B=32, H*W=256.
//
// Outputs (float32, concatenated):
//   [0 .. 262144)        z_q_out [B,C,H,W]  (z_q_st == z_q in value)
//   [262144]             loss (scalar)
//   [262145 .. 270337)   token_ids [B,H,W] as float
//   [270337 .. 532481)   new_embedding [K,C]
//   [532481 .. 540673)   new_cluster_sizes [K]

#define NTOK   8192
#define NCODE  8192
#define CDIM   32
#define HW     256
#define DECAYF 0.99f

#define OUT_ZQ   0
#define OUT_LOSS 262144
#define OUT_IDS  262145
#define OUT_EMB  270337
#define OUT_CS   532481

// workspace byte offsets
#define WS_ZN    0u         // 8192*32 f32 = 1 MiB
#define WS_PACK  1048576u   // 8192 u64   = 64 KiB
#define WS_BINS  1114112u   // 8192 i32   = 32 KiB
#define WS_ESUM  1146880u   // 8192*32 f32= 1 MiB
#define WS_IDS   2195456u   // 8192 i32   = 32 KiB
#define WS_LOSS  2228224u   // 1 f32
#define WS_END   2228228u
#define WS_ZERO_BYTES (WS_END - WS_PACK)

// ---------------- Kernel A: channel-last transpose + L2 normalize ----------------
__global__ __launch_bounds__(256) void k_norm(const float* __restrict__ z,
                                              float* __restrict__ zn) {
    int n = blockIdx.x * 256 + threadIdx.x;       // token = b*256 + hw
    int b = n >> 8, hw = n & 255;
    const float* zp = z + (size_t)b * (CDIM * HW) + hw;
    float v[CDIM];
    float ss = 0.f;
#pragma unroll
    for (int c = 0; c < CDIM; ++c) {
        float t = zp[c * HW];                     // coalesced across lanes per c
        v[c] = t;
        ss += t * t;
    }
    float d = fmaxf(sqrtf(ss), 1e-12f);
    float* o = zn + (size_t)n * CDIM;
#pragma unroll
    for (int c = 0; c < CDIM; ++c) o[c] = v[c] / d;
}

// ---------------- Kernel B: fused matmul + argmax (the hot loop) ----------------
// grid (32 token-blocks, 32 K-chunks), 256 thr: lane=token, chunk=256 codes.
// Code row index is wave-uniform -> scalar loads; 32 VALU FMAs per code per lane.
__global__ __launch_bounds__(256) void k_argmax(const float* __restrict__ zn,
                                                const float* __restrict__ emb,
                                                unsigned long long* __restrict__ packed) {
    int token = blockIdx.x * 256 + threadIdx.x;
    const float4* zp = (const float4*)(zn + (size_t)token * CDIM);
    float4 z0 = zp[0], z1 = zp[1], z2 = zp[2], z3 = zp[3];
    float4 z4 = zp[4], z5 = zp[5], z6 = zp[6], z7 = zp[7];

    int kbase = blockIdx.y * 256;
    const float* e = emb + (size_t)kbase * CDIM;
    float best = -1e30f;
    int bidx = kbase;
    for (int kk = 0; kk < 256; ++kk) {
        const float4* ef = (const float4*)e;
        float4 e0 = ef[0], e1 = ef[1], e2 = ef[2], e3 = ef[3];
        float4 e4 = ef[4], e5 = ef[5], e6 = ef[6], e7 = ef[7];
        float acc = z0.x * e0.x;
        acc += z0.y * e0.y; acc += z0.z * e0.z; acc += z0.w * e0.w;
        acc += z1.x * e1.x; acc += z1.y * e1.y; acc += z1.z * e1.z; acc += z1.w * e1.w;
        acc += z2.x * e2.x; acc += z2.y * e2.y; acc += z2.z * e2.z; acc += z2.w * e2.w;
        acc += z3.x * e3.x; acc += z3.y * e3.y; acc += z3.z * e3.z; acc += z3.w * e3.w;
        acc += z4.x * e4.x; acc += z4.y * e4.y; acc += z4.z * e4.z; acc += z4.w * e4.w;
        acc += z5.x * e5.x; acc += z5.y * e5.y; acc += z5.z * e5.z; acc += z5.w * e5.w;
        acc += z6.x * e6.x; acc += z6.y * e6.y; acc += z6.z * e6.z; acc += z6.w * e6.w;
        acc += z7.x * e7.x; acc += z7.y * e7.y; acc += z7.z * e7.z; acc += z7.w * e7.w;
        if (acc > best) { best = acc; bidx = kbase + kk; }   // strict > keeps lowest k
        e += CDIM;
    }
    // monotonic float->u32 map, then pack with inverted idx so max => lowest idx on tie
    unsigned u = __float_as_uint(best);
    u = (u & 0x80000000u) ? ~u : (u | 0x80000000u);
    unsigned long long key =
        ((unsigned long long)u << 13) | (unsigned long long)(8191 - bidx);
    atomicMax(packed + token, key);
}

// ---------------- Kernel C: unpack ids + scatter (bins, embed_sum) ----------------
__global__ __launch_bounds__(256) void k_scatter(const unsigned long long* __restrict__ packed,
                                                 const float* __restrict__ zn,
                                                 int* __restrict__ bins,
                                                 float* __restrict__ esum,
                                                 int* __restrict__ ids,
                                                 float* __restrict__ out_ids) {
    int n = blockIdx.x * 256 + threadIdx.x;
    unsigned long long key = packed[n];
    int id = 8191 - (int)(key & 8191ull);
    ids[n] = id;
    out_ids[n] = (float)id;
    atomicAdd(bins + id, 1);
    const float* zp = zn + (size_t)n * CDIM;
    float* ep = esum + (size_t)id * CDIM;
#pragma unroll
    for (int c = 0; c < CDIM; ++c) atomicAdd(ep + c, zp[c]);
}

// ---------------- Kernel E: z_q gather + transpose-out + loss partial ----------------
__global__ __launch_bounds__(256) void k_output(const int* __restrict__ ids,
                                                const float* __restrict__ emb,
                                                const float* __restrict__ zn,
                                                float* __restrict__ out,
                                                float* __restrict__ loss_acc) {
    int n = blockIdx.x * 256 + threadIdx.x;
    int b = n >> 8, hw = n & 255;
    int id = ids[n];
    const float* e = emb + (size_t)id * CDIM;
    const float* zp = zn + (size_t)n * CDIM;
    float s = 0.f;
#pragma unroll
    for (int c = 0; c < CDIM; ++c) {
        float ev = e[c];
        float dd = ev - zp[c];
        s += dd * dd;
        out[OUT_ZQ + ((size_t)b * CDIM + c) * HW + hw] = ev;  // coalesced per c
    }
#pragma unroll
    for (int off = 32; off > 0; off >>= 1) s += __shfl_down(s, off);
    if ((threadIdx.x & 63) == 0) atomicAdd(loss_acc, s);
}

// ---------------- Kernel D: EMA update, renormalize, write loss/emb/cs ----------------
__global__ __launch_bounds__(256) void k_update(const float* __restrict__ emb,
                                                const float* __restrict__ cs,
                                                const int* __restrict__ bins,
                                                const float* __restrict__ esum,
                                                const float* __restrict__ loss_acc,
                                                float* __restrict__ out) {
    int k = blockIdx.x * 256 + threadIdx.x;
    if (k == 0) out[OUT_LOSS] = loss_acc[0] * (1.0f / 262144.0f);
    int bi = bins[k];
    float bf = (float)bi;
    out[OUT_CS + k] = cs[k] * DECAYF + (1.0f - DECAYF) * bf;
    bool zero = (bi == 0);
    float bc = zero ? 1.0f : bf;
    float v[CDIM];
    float ss = 0.f;
#pragma unroll
    for (int c = 0; c < CDIM; ++c) {
        float t = esum[(size_t)k * CDIM + c] / bc;
        v[c] = t;
        ss += t * t;
    }
    float d = fmaxf(sqrtf(ss), 1e-12f);
    float w[CDIM];
    float ss2 = 0.f;
#pragma unroll
    for (int c = 0; c < CDIM; ++c) {
        float ew = emb[(size_t)k * CDIM + c];
        float en = zero ? ew : (v[c] / d);
        float t = ew * DECAYF + (1.0f - DECAYF) * en;
        w[c] = t;
        ss2 += t * t;
    }
    float d2 = fmaxf(sqrtf(ss2), 1e-12f);
#pragma unroll
    for (int c = 0; c < CDIM; ++c)
        out[OUT_EMB + (size_t)k * CDIM + c] = w[c] / d2;
}

extern "C" void kernel_launch(void* const* d_in, const int* in_sizes, int n_in,
                              void* d_out, int out_size, void* d_ws, size_t ws_size,
                              hipStream_t stream) {
    const float* z   = (const float*)d_in[0];   // [32,32,16,16]
    const float* emb = (const float*)d_in[1];   // [8192,32]
    const float* cs  = (const float*)d_in[2];   // [8192]
    float* out = (float*)d_out;
    char* ws = (char*)d_ws;

    float* zn                    = (float*)(ws + WS_ZN);
    unsigned long long* packed   = (unsigned long long*)(ws + WS_PACK);
    int* bins                    = (int*)(ws + WS_BINS);
    float* esum                  = (float*)(ws + WS_ESUM);
    int* ids                     = (int*)(ws + WS_IDS);
    float* loss_acc              = (float*)(ws + WS_LOSS);

    hipMemsetAsync(ws + WS_PACK, 0, WS_ZERO_BYTES, stream);

    k_norm<<<dim3(NTOK / 256), 256, 0, stream>>>(z, zn);
    k_argmax<<<dim3(NTOK / 256, NCODE / 256), 256, 0, stream>>>(zn, emb, packed);
    k_scatter<<<dim3(NTOK / 256), 256, 0, stream>>>(packed, zn, bins, esum, ids,
                                                    out + OUT_IDS);
    k_output<<<dim3(NTOK / 256), 256, 0, stream>>>(ids, emb, zn, out, loss_acc);
    k_update<<<dim3(NCODE / 256), 256, 0, stream>>>(emb, cs, bins, esum, loss_acc, out);
}

// Round 2
// 173.411 us; speedup vs baseline: 1.0505x; 1.0505x over previous
//
#include <hip/hip_runtime.h>

// NormEMAVectorQuantizer on MI355X (gfx950)
// N=8192 tokens, C=32, K=8192 codes, B=32, H*W=256.
//
// Outputs (float32, concatenated):
//   [0 .. 262144)        z_q_out [B,C,H,W]
//   [262144]             loss (scalar)
//   [262145 .. 270337)   token_ids [B,H,W] as float
//   [270337 .. 532481)   new_embedding [K,C]
//   [532481 .. 540673)   new_cluster_sizes [K]

#define NTOK   8192
#define NCODE  8192
#define CDIM   32
#define HW     256
#define DECAYF 0.99f

#define OUT_ZQ   0
#define OUT_LOSS 262144
#define OUT_IDS  262145
#define OUT_EMB  270337
#define OUT_CS   532481

// workspace byte offsets
#define WS_ZN    0u         // 8192*32 f32 = 1 MiB
#define WS_PACK  1048576u   // 8192 u64   = 64 KiB
#define WS_BINS  1114112u   // 8192 i32   = 32 KiB
#define WS_ESUM  1146880u   // 8192*32 f32= 1 MiB
#define WS_LOSS  2195456u   // 1 f32
#define WS_END   2195460u
#define WS_ZERO_BYTES (WS_END - WS_PACK)

// ---------------- Kernel A: channel-last transpose + L2 normalize ----------------
__global__ __launch_bounds__(256) void k_norm(const float* __restrict__ z,
                                              float* __restrict__ zn) {
    int n = blockIdx.x * 256 + threadIdx.x;       // token = b*256 + hw
    int b = n >> 8, hw = n & 255;
    const float* zp = z + (size_t)b * (CDIM * HW) + hw;
    float v[CDIM];
    float ss = 0.f;
#pragma unroll
    for (int c = 0; c < CDIM; ++c) {
        float t = zp[c * HW];                     // coalesced across lanes per c
        v[c] = t;
        ss += t * t;
    }
    float d = fmaxf(sqrtf(ss), 1e-12f);
    float* o = zn + (size_t)n * CDIM;
#pragma unroll
    for (int c = 0; c < CDIM; ++c) o[c] = v[c] / d;
}

// ---------------- Kernel B: fused matmul + argmax (the hot loop) ----------------
// T=2 tokens per lane: each uniform (scalar) e-row load feeds 64 FMAs.
// grid.x = 16 token-blocks (512 tokens each), grid.y = 64 K-chunks (128 codes).
// 4 independent accumulator chains per token break FMA latency serialization.
__global__ __launch_bounds__(256) void k_argmax(const float* __restrict__ zn,
                                                const float* __restrict__ emb,
                                                unsigned long long* __restrict__ packed) {
    int t0 = blockIdx.x * 512 + threadIdx.x;      // token 0
    int t1 = t0 + 256;                            // token 1
    float za[CDIM], zb[CDIM];
    {
        const float4* p0 = (const float4*)(zn + (size_t)t0 * CDIM);
        const float4* p1 = (const float4*)(zn + (size_t)t1 * CDIM);
#pragma unroll
        for (int j = 0; j < 8; ++j) {
            float4 a = p0[j];
            za[4 * j + 0] = a.x; za[4 * j + 1] = a.y; za[4 * j + 2] = a.z; za[4 * j + 3] = a.w;
            float4 b = p1[j];
            zb[4 * j + 0] = b.x; zb[4 * j + 1] = b.y; zb[4 * j + 2] = b.z; zb[4 * j + 3] = b.w;
        }
    }

    int kbase = blockIdx.y * 128;
    const float* e = emb + (size_t)kbase * CDIM;  // wave-uniform -> scalar loads
    float best0 = -1e30f, best1 = -1e30f;
    int bi0 = kbase, bi1 = kbase;

    for (int kk = 0; kk < 128; ++kk) {
        const float* er = e + kk * CDIM;
        float a0 = 0.f, a1 = 0.f, a2 = 0.f, a3 = 0.f;   // token0 partial chains
        float b0 = 0.f, b1 = 0.f, b2 = 0.f, b3 = 0.f;   // token1 partial chains
#pragma unroll
        for (int j = 0; j < 8; ++j) {
            float e0 = er[4 * j + 0], e1 = er[4 * j + 1], e2 = er[4 * j + 2], e3 = er[4 * j + 3];
            a0 = __builtin_fmaf(za[4 * j + 0], e0, a0);
            a1 = __builtin_fmaf(za[4 * j + 1], e1, a1);
            a2 = __builtin_fmaf(za[4 * j + 2], e2, a2);
            a3 = __builtin_fmaf(za[4 * j + 3], e3, a3);
            b0 = __builtin_fmaf(zb[4 * j + 0], e0, b0);
            b1 = __builtin_fmaf(zb[4 * j + 1], e1, b1);
            b2 = __builtin_fmaf(zb[4 * j + 2], e2, b2);
            b3 = __builtin_fmaf(zb[4 * j + 3], e3, b3);
        }
        float sa = (a0 + a1) + (a2 + a3);
        float sb = (b0 + b1) + (b2 + b3);
        if (sa > best0) { best0 = sa; bi0 = kbase + kk; }  // strict > keeps lowest k
        if (sb > best1) { best1 = sb; bi1 = kbase + kk; }
    }

    // monotonic float->u32 map, pack with inverted idx so max => lowest idx on tie
    unsigned u0 = __float_as_uint(best0);
    u0 = (u0 & 0x80000000u) ? ~u0 : (u0 | 0x80000000u);
    unsigned u1 = __float_as_uint(best1);
    u1 = (u1 & 0x80000000u) ? ~u1 : (u1 | 0x80000000u);
    atomicMax(packed + t0, ((unsigned long long)u0 << 13) | (unsigned long long)(8191 - bi0));
    atomicMax(packed + t1, ((unsigned long long)u1 << 13) | (unsigned long long)(8191 - bi1));
}

// ------- Kernel C: unpack ids, scatter (bins, esum), z_q gather + loss -------
__global__ __launch_bounds__(256) void k_scatter_out(const unsigned long long* __restrict__ packed,
                                                     const float* __restrict__ zn,
                                                     const float* __restrict__ emb,
                                                     int* __restrict__ bins,
                                                     float* __restrict__ esum,
                                                     float* __restrict__ out,
                                                     float* __restrict__ loss_acc) {
    int n = blockIdx.x * 256 + threadIdx.x;
    int b = n >> 8, hw = n & 255;
    unsigned long long key = packed[n];
    int id = 8191 - (int)(key & 8191ull);
    out[OUT_IDS + n] = (float)id;
    atomicAdd(bins + id, 1);
    const float* zp = zn + (size_t)n * CDIM;
    const float* ep = emb + (size_t)id * CDIM;
    float* sp = esum + (size_t)id * CDIM;
    float s = 0.f;
#pragma unroll
    for (int c = 0; c < CDIM; ++c) {
        float zv = zp[c];
        float ev = ep[c];
        float dd = ev - zv;
        s += dd * dd;
        atomicAdd(sp + c, zv);
        out[OUT_ZQ + ((size_t)b * CDIM + c) * HW + hw] = ev;  // coalesced per c
    }
#pragma unroll
    for (int off = 32; off > 0; off >>= 1) s += __shfl_down(s, off);
    if ((threadIdx.x & 63) == 0) atomicAdd(loss_acc, s);
}

// ---------------- Kernel D: EMA update, renormalize, write loss/emb/cs ----------------
__global__ __launch_bounds__(256) void k_update(const float* __restrict__ emb,
                                                const float* __restrict__ cs,
                                                const int* __restrict__ bins,
                                                const float* __restrict__ esum,
                                                const float* __restrict__ loss_acc,
                                                float* __restrict__ out) {
    int k = blockIdx.x * 256 + threadIdx.x;
    if (k == 0) out[OUT_LOSS] = loss_acc[0] * (1.0f / 262144.0f);
    int bi = bins[k];
    float bf = (float)bi;
    out[OUT_CS + k] = cs[k] * DECAYF + (1.0f - DECAYF) * bf;
    bool zero = (bi == 0);
    float bc = zero ? 1.0f : bf;
    float v[CDIM];
    float ss = 0.f;
#pragma unroll
    for (int c = 0; c < CDIM; ++c) {
        float t = esum[(size_t)k * CDIM + c] / bc;
        v[c] = t;
        ss += t * t;
    }
    float d = fmaxf(sqrtf(ss), 1e-12f);
    float w[CDIM];
    float ss2 = 0.f;
#pragma unroll
    for (int c = 0; c < CDIM; ++c) {
        float ew = emb[(size_t)k * CDIM + c];
        float en = zero ? ew : (v[c] / d);
        float t = ew * DECAYF + (1.0f - DECAYF) * en;
        w[c] = t;
        ss2 += t * t;
    }
    float d2 = fmaxf(sqrtf(ss2), 1e-12f);
#pragma unroll
    for (int c = 0; c < CDIM; ++c)
        out[OUT_EMB + (size_t)k * CDIM + c] = w[c] / d2;
}

extern "C" void kernel_launch(void* const* d_in, const int* in_sizes, int n_in,
                              void* d_out, int out_size, void* d_ws, size_t ws_size,
                              hipStream_t stream) {
    const float* z   = (const float*)d_in[0];   // [32,32,16,16]
    const float* emb = (const float*)d_in[1];   // [8192,32]
    const float* cs  = (const float*)d_in[2];   // [8192]
    float* out = (float*)d_out;
    char* ws = (char*)d_ws;

    float* zn                    = (float*)(ws + WS_ZN);
    unsigned long long* packed   = (unsigned long long*)(ws + WS_PACK);
    int* bins                    = (int*)(ws + WS_BINS);
    float* esum                  = (float*)(ws + WS_ESUM);
    float* loss_acc              = (float*)(ws + WS_LOSS);

    hipMemsetAsync(ws + WS_PACK, 0, WS_ZERO_BYTES, stream);

    k_norm<<<dim3(NTOK / 256), 256, 0, stream>>>(z, zn);
    k_argmax<<<dim3(NTOK / 512, NCODE / 128), 256, 0, stream>>>(zn, emb, packed);
    k_scatter_out<<<dim3(NTOK / 256), 256, 0, stream>>>(packed, zn, emb, bins, esum,
                                                        out, loss_acc);
    k_update<<<dim3(NCODE / 256), 256, 0, stream>>>(emb, cs, bins, esum, loss_acc, out);
}